// Round 6
// baseline (203.753 us; speedup 1.0000x reference)
//
#include <hip/hip_runtime.h>
#include <math.h>

#define FT_OUT 256
#define VFT 640
#define CAP 96      // per-row bucket capacity; Poisson(32) max ~56-60, 96 = +11 sigma
#define SLICE 32    // outputs per XCD slice
#define NSLICE 8    // FT_OUT / SLICE == number of XCDs

typedef _Float16 half8_t __attribute__((ext_vector_type(8)));
typedef _Float16 half2_t __attribute__((ext_vector_type(2)));

// ---- merged prep: blocks [0, nfill) fill slots (side-split); rest build W2s ----
// W2s layout: [slice][col][32]  i.e. index(col,o) = ((o>>5)*ft_in + col)*32 + (o&31)
// W2s value = (half)(ft_w[o][col] + fft_w[o][col%640])
__global__ __launch_bounds__(256) void prep_k(
    const float* __restrict__ ft_w, const float* __restrict__ fft_w,
    _Float16* __restrict__ W2s, int ft_in,
    const int* __restrict__ stm, const int* __restrict__ nstm,
    const float* __restrict__ vals, int nnz,
    int* __restrict__ cnt_s, int* __restrict__ cnt_n,
    int2* __restrict__ slot_s, int2* __restrict__ slot_n, int nfill)
{
    int bx = (int)blockIdx.x;
    if (bx < nfill) {  // fill: one side per block for 2x chain parallelism
        int side = bx & 1;
        int k = (bx >> 1) * 256 + threadIdx.x;
        if (k >= nnz) return;
        const int* src = side ? nstm : stm;
        int* cnt = side ? cnt_n : cnt_s;
        int2* slotb = side ? slot_n : slot_s;
        int r = src[k], c = src[nnz + k];
        int vb = __float_as_int(vals[k]);
        int pos = atomicAdd(&cnt[r], 1);
        if (pos < CAP) slotb[(size_t)r * CAP + pos] = make_int2(c, vb);
        return;
    }
    // build: pre-add ft+fft during load -> single LDS tile
    __shared__ float tile[64][65];  // [out][col], sum of ft+fft
    bx -= nfill;
    int cb = (bx >> 2) * 64;     // 640 col tiles
    int ob = (bx & 3) * 64;      // 4 out tiles
    int fvb = cb % VFT;          // 640 % 64 == 0 -> contiguous 64-col window
    int tc4 = threadIdx.x & 15, tr = threadIdx.x >> 4;
#pragma unroll
    for (int i = 0; i < 4; i++) {
        int o = i * 16 + tr;
        const float4 f = *(const float4*)(ft_w + (size_t)(ob + o) * ft_in + cb + tc4 * 4);
        const float4 g = *(const float4*)(fft_w + (size_t)(ob + o) * VFT + fvb + tc4 * 4);
        tile[o][tc4 * 4 + 0] = f.x + g.x; tile[o][tc4 * 4 + 1] = f.y + g.y;
        tile[o][tc4 * 4 + 2] = f.z + g.z; tile[o][tc4 * 4 + 3] = f.w + g.w;
    }
    __syncthreads();
    int g = threadIdx.x & 7, cl = threadIdx.x >> 3;
#pragma unroll
    for (int i = 0; i < 2; i++) {
        int c = i * 32 + cl, col = cb + c;
        int obase = ob + g * 8;
        int slice = obase >> 5, sub = obase & 31;  // sub in {0,8,16,24}
        half8_t h;
#pragma unroll
        for (int jj = 0; jj < 8; jj++) h[jj] = (_Float16)tile[g * 8 + jj][c];
        *(half8_t*)(W2s + (((size_t)(slice * ft_in + col)) << 5) + sub) = h;
    }
}

// ---- XCD-sliced gather: blockIdx%8 = slice (2.5 MB table slice, L2-resident) ----
// One wave per (row-of-4-block, wave): handles 1 row, both sides, for its slice.
// Lane: ent = lane>>4 (4 parallel entries), oo = (lane&15)*2 (2 outputs via ushort2).
__global__ __launch_bounds__(256) void gather_k(
    const _Float16* __restrict__ W2s,
    const int* __restrict__ cnt_s, const int2* __restrict__ slot_s,
    const int* __restrict__ cnt_n, const int2* __restrict__ slot_n,
    const float* __restrict__ ft_b, const float* __restrict__ fft_b,
    const float* __restrict__ out_w, float* __restrict__ racc, int ft_in)
{
    int slice = blockIdx.x & 7;
    int grp   = blockIdx.x >> 3;
    int wid   = threadIdx.x >> 6;
    int lane  = threadIdx.x & 63;
    int row   = grp * 4 + wid;
    int ent   = lane >> 4;           // 0..3: parallel entry index
    int oo    = (lane & 15) * 2;     // output pair within slice
    const _Float16* Wt = W2s + (((size_t)slice * ft_in) << 5) + oo;
    int og = slice * SLICE + oo;
    const float2 bias2 = make_float2(ft_b[og] + fft_b[og], ft_b[og + 1] + fft_b[og + 1]);

    float wsum = 0.f;
#pragma unroll
    for (int side = 0; side < 2; side++) {
        const int*  cnt  = side ? cnt_n : cnt_s;
        const int2* slot = (side ? slot_n : slot_s) + (size_t)row * CAP;
        int n = min(cnt[row], CAP);
        float a0 = (ent == 0) ? bias2.x : 0.f;
        float a1 = (ent == 0) ? bias2.y : 0.f;
        int steps = (n + 3) >> 2;
        int s = 0;
        for (; s + 2 <= steps; s += 2) {  // 2 slot + 2 weight loads in flight
            int i0 = s * 4 + ent, i1 = i0 + 4;
            int2 e0 = slot[i0 < n ? i0 : 0];
            int2 e1 = slot[i1 < n ? i1 : 0];
            float v0 = (i0 < n) ? __int_as_float(e0.y) : 0.f;
            float v1 = (i1 < n) ? __int_as_float(e1.y) : 0.f;
            const half2_t w0 = *(const half2_t*)(Wt + ((size_t)e0.x << 5));
            const half2_t w1 = *(const half2_t*)(Wt + ((size_t)e1.x << 5));
            a0 += v0 * (float)w0[0]; a1 += v0 * (float)w0[1];
            a0 += v1 * (float)w1[0]; a1 += v1 * (float)w1[1];
        }
        if (s < steps) {
            int i0 = s * 4 + ent;
            int2 e0 = slot[i0 < n ? i0 : 0];
            float v0 = (i0 < n) ? __int_as_float(e0.y) : 0.f;
            const half2_t w0 = *(const half2_t*)(Wt + ((size_t)e0.x << 5));
            a0 += v0 * (float)w0[0]; a1 += v0 * (float)w0[1];
        }
        // reduce over the 4 ent groups (lanes l, l^16, l^32, l^48)
        a0 += __shfl_xor(a0, 16, 64); a1 += __shfl_xor(a1, 16, 64);
        a0 += __shfl_xor(a0, 32, 64); a1 += __shfl_xor(a1, 32, 64);
        // clip + partial dot with out_w slice
        a0 = fminf(fmaxf(a0, 0.f), 1.f);
        a1 = fminf(fmaxf(a1, 0.f), 1.f);
        const float2 ow = *(const float2*)(out_w + side * FT_OUT + og);
        wsum += a0 * ow.x + a1 * ow.y;
    }
    // sum over the 16 output-pair lanes (dup x4 across ent groups)
#pragma unroll
    for (int m = 1; m <= 8; m <<= 1) wsum += __shfl_xor(wsum, m, 64);
    if (lane == 0) atomicAdd(&racc[row], wsum);
}

// ---- epilogue: sigmoid over per-row sums ----
__global__ void sigmoid_k(const float* __restrict__ racc, const float* __restrict__ out_b,
                          float* __restrict__ out, int B) {
    int i = blockIdx.x * 256 + threadIdx.x;
    if (i < B) out[i] = 1.f / (1.f + __expf(-(racc[i] + out_b[0])));
}

extern "C" void kernel_launch(void* const* d_in, const int* in_sizes, int n_in,
                              void* d_out, int out_size, void* d_ws, size_t ws_size,
                              hipStream_t stream) {
    const int*   stm    = (const int*)d_in[0];   // [2, NNZ]: rows then cols
    const int*   nstm   = (const int*)d_in[1];
    const float* values = (const float*)d_in[2];
    const float* ft_w   = (const float*)d_in[4];
    const float* ft_b   = (const float*)d_in[5];
    const float* fft_w  = (const float*)d_in[6];
    const float* fft_b  = (const float*)d_in[7];
    const float* out_w  = (const float*)d_in[8];
    const float* out_b  = (const float*)d_in[9];
    float* out = (float*)d_out;

    int B = out_size;                 // 8192
    int nnz = in_sizes[0] / 2;        // 262144
    int ft_in = in_sizes[4] / FT_OUT; // 40960

    // workspace layout (16B-aligned pieces); cnt_s/cnt_n/racc contiguous for one memset
    _Float16* W2s  = (_Float16*)d_ws;                          // ft_in*256 halfs (20 MB)
    int2*  slot_s  = (int2*)(W2s + (size_t)ft_in * FT_OUT);    // B*CAP entries (6 MB)
    int2*  slot_n  = slot_s + (size_t)B * CAP;                 // 6 MB
    int*   cnt_s   = (int*)(slot_n + (size_t)B * CAP);         // B
    int*   cnt_n   = cnt_s + B;                                // B
    float* racc    = (float*)(cnt_n + B);                      // B

    int nfill  = 2 * ((nnz + 255) / 256);                      // 2048
    int nbuild = (ft_in / 64) * (FT_OUT / 64);                 // 2560

    hipMemsetAsync(cnt_s, 0, 3 * (size_t)B * sizeof(int), stream);
    prep_k<<<nfill + nbuild, 256, 0, stream>>>(ft_w, fft_w, W2s, ft_in,
                                               stm, nstm, values, nnz,
                                               cnt_s, cnt_n, slot_s, slot_n, nfill);
    gather_k<<<(B / 4) * NSLICE, 256, 0, stream>>>(W2s, cnt_s, slot_s, cnt_n, slot_n,
                                                   ft_b, fft_b, out_w, racc, ft_in);
    sigmoid_k<<<(B + 255) / 256, 256, 0, stream>>>(racc, out_b, out, B);
}

// Round 7
// 163.333 us; speedup vs baseline: 1.2475x; 1.2475x over previous
//
#include <hip/hip_runtime.h>
#include <math.h>

#define FT_OUT 256
#define VFT 640
#define CAP 96        // per-row bucket capacity; Poisson(32) max ~56-60, 96 = +11 sigma
#define CPAD 16       // counter stride in ints (64 B) to kill same-line atomic serialization

typedef _Float16 half8_t __attribute__((ext_vector_type(8)));
typedef float    float8_t __attribute__((ext_vector_type(8)));

// ---- merged prep: blocks [0, nfill) fill slots (side-split); rest build W2h ----
// W2h[col][o] = (half)(ft_w[o][col] + fft_w[o][col%640])
__global__ __launch_bounds__(256) void prep_k(
    const float* __restrict__ ft_w, const float* __restrict__ fft_w,
    _Float16* __restrict__ W2h, int ft_in,
    const int* __restrict__ stm, const int* __restrict__ nstm,
    const float* __restrict__ vals, int nnz,
    int* __restrict__ cnt_s, int* __restrict__ cnt_n,
    int2* __restrict__ slot_s, int2* __restrict__ slot_n, int nfill)
{
    int bx = (int)blockIdx.x;
    if (bx < nfill) {  // fill: one side per block for 2x chain parallelism
        int side = bx & 1;
        int k = (bx >> 1) * 256 + threadIdx.x;
        if (k >= nnz) return;
        const int* src = side ? nstm : stm;
        int* cnt = side ? cnt_n : cnt_s;
        int2* slotb = side ? slot_n : slot_s;
        int r = src[k], c = src[nnz + k];
        int vb = __float_as_int(vals[k]);
        int pos = atomicAdd(&cnt[r * CPAD], 1);   // padded: 1 counter per 64B line
        if (pos < CAP) slotb[(size_t)r * CAP + pos] = make_int2(c, vb);
        return;
    }
    // build: pre-add ft+fft during load -> single LDS tile
    __shared__ float tile[64][65];  // [out][col], sum of ft+fft
    bx -= nfill;
    int cb = (bx >> 2) * 64;     // 640 col tiles
    int ob = (bx & 3) * 64;      // 4 out tiles
    int fvb = cb % VFT;          // 640 % 64 == 0 -> contiguous 64-col window
    int tc4 = threadIdx.x & 15, tr = threadIdx.x >> 4;
#pragma unroll
    for (int i = 0; i < 4; i++) {
        int o = i * 16 + tr;
        const float4 f = *(const float4*)(ft_w + (size_t)(ob + o) * ft_in + cb + tc4 * 4);
        const float4 g = *(const float4*)(fft_w + (size_t)(ob + o) * VFT + fvb + tc4 * 4);
        tile[o][tc4 * 4 + 0] = f.x + g.x; tile[o][tc4 * 4 + 1] = f.y + g.y;
        tile[o][tc4 * 4 + 2] = f.z + g.z; tile[o][tc4 * 4 + 3] = f.w + g.w;
    }
    __syncthreads();
    int g = threadIdx.x & 7, cl = threadIdx.x >> 3;
#pragma unroll
    for (int i = 0; i < 2; i++) {
        int c = i * 32 + cl, col = cb + c;
        half8_t h;
#pragma unroll
        for (int jj = 0; jj < 8; jj++) h[jj] = (_Float16)tile[g * 8 + jj][c];
        *(half8_t*)(W2h + (size_t)col * FT_OUT + ob + g * 8) = h;
    }
}

// ------- fused gather + clip + head + sigmoid: one wave per (row, side) -------
// Lane halves: lanes 0-31 process even slot entries, 32-63 odd; each lane loads
// half8 (16B) covering 8 outputs at chunk (lane&31). Slot loads are non-temporal
// so the once-streamed 12 MB of slots don't evict W2h lines from L2.
__global__ __launch_bounds__(256) void fused_k(const _Float16* __restrict__ W2h,
    const int* __restrict__ cnt_s, const int2* __restrict__ slot_s,
    const int* __restrict__ cnt_n, const int2* __restrict__ slot_n,
    const float* __restrict__ ft_b, const float* __restrict__ fft_b,
    const float* __restrict__ out_w, const float* __restrict__ out_b,
    float* __restrict__ out, int B) {
    int lane = threadIdx.x & 63;
    int wid  = threadIdx.x >> 6;            // 0..3
    int row  = blockIdx.x * 2 + (wid >> 1); // 2 rows per block
    int side = wid & 1;                     // 0 = stm, 1 = nstm
    int hi   = lane >> 5;                   // 0 or 1: which slot entry of a pair
    int sl   = lane & 31;                   // 8-output chunk index

    const int*  cnt  = side ? cnt_n : cnt_s;
    const int2* slot = (side ? slot_n : slot_s) + (size_t)row * CAP;
    int n = min(cnt[row * CPAD], CAP);

    float8_t acc;
#pragma unroll
    for (int k = 0; k < 8; k++) acc[k] = 0.f;
    if (hi == 0) {  // bias only once across the two halves
        const float4* fb = (const float4*)(ft_b + sl * 8);
        const float4* gb = (const float4*)(fft_b + sl * 8);
        float4 a0 = fb[0], a1 = fb[1], c0 = gb[0], c1 = gb[1];
        acc[0] = a0.x + c0.x; acc[1] = a0.y + c0.y; acc[2] = a0.z + c0.z; acc[3] = a0.w + c0.w;
        acc[4] = a1.x + c1.x; acc[5] = a1.y + c1.y; acc[6] = a1.z + c1.z; acc[7] = a1.w + c1.w;
    }

    // non-temporal 8B pair loads of a 16B slot pair (j even, 16B-aligned)
#define LOADPAIR(j, cc, vv)                                                         \
    {                                                                               \
        unsigned long long p0 =                                                     \
            __builtin_nontemporal_load((const unsigned long long*)(slot + (j)));    \
        unsigned long long p1 =                                                     \
            __builtin_nontemporal_load((const unsigned long long*)(slot + (j)) + 1);\
        unsigned long long pe = hi ? p1 : p0;                                       \
        cc = (int)(pe & 0xffffffffu);                                               \
        vv = __int_as_float((int)(pe >> 32));                                       \
    }
#define PROC(cc, vv)                                                                \
    {                                                                               \
        const half8_t w_ = *(const half8_t*)(W2h + ((size_t)(cc) << 8) + (sl << 3));\
        _Pragma("unroll")                                                           \
        for (int k = 0; k < 8; k++) acc[k] += (vv) * (float)w_[k];                  \
    }

    int j = 0;
    for (; j + 8 <= n; j += 8) {  // 8 slot-half + 4 weight loads in flight
        int c0, c1, c2, c3; float v0, v1, v2, v3;
        LOADPAIR(j,     c0, v0)
        LOADPAIR(j + 2, c1, v1)
        LOADPAIR(j + 4, c2, v2)
        LOADPAIR(j + 6, c3, v3)
        PROC(c0, v0) PROC(c1, v1) PROC(c2, v2) PROC(c3, v3)
    }
    for (; j + 2 <= n; j += 2) {
        int c0; float v0;
        LOADPAIR(j, c0, v0)
        PROC(c0, v0)
    }
    if (j < n) {  // odd tail: high half contributes zero via dummy col 0
        const int2 e = slot[j];
        int   c_ = hi ? 0 : e.x;
        float v_ = hi ? 0.f : __int_as_float(e.y);
        PROC(c_, v_)
    }
#undef PROC
#undef LOADPAIR

    // combine the two lane-halves (lane l and l^32 own the same 8 outputs), clip
#pragma unroll
    for (int k = 0; k < 8; k++) {
        float o = __shfl_xor(acc[k], 32, 64);
        acc[k] = fminf(fmaxf(acc[k] + o, 0.f), 1.f);
    }

    const float4* ow = (const float4*)(out_w + side * FT_OUT + sl * 8);
    const float4 w0 = ow[0], w1 = ow[1];
    float p = acc[0] * w0.x + acc[1] * w0.y + acc[2] * w0.z + acc[3] * w0.w
            + acc[4] * w1.x + acc[5] * w1.y + acc[6] * w1.z + acc[7] * w1.w;
#pragma unroll
    for (int m = 32; m >= 1; m >>= 1) p += __shfl_xor(p, m, 64);
    p *= 0.5f;  // both halves duplicated the per-chunk partials

    __shared__ float part[4];
    if (lane == 0) part[wid] = p;
    __syncthreads();
    if (threadIdx.x < 2) {
        float q = part[threadIdx.x * 2] + part[threadIdx.x * 2 + 1] + out_b[0];
        out[blockIdx.x * 2 + threadIdx.x] = 1.f / (1.f + __expf(-q));
    }
}

extern "C" void kernel_launch(void* const* d_in, const int* in_sizes, int n_in,
                              void* d_out, int out_size, void* d_ws, size_t ws_size,
                              hipStream_t stream) {
    const int*   stm    = (const int*)d_in[0];   // [2, NNZ]: rows then cols
    const int*   nstm   = (const int*)d_in[1];
    const float* values = (const float*)d_in[2];
    const float* ft_w   = (const float*)d_in[4];
    const float* ft_b   = (const float*)d_in[5];
    const float* fft_w  = (const float*)d_in[6];
    const float* fft_b  = (const float*)d_in[7];
    const float* out_w  = (const float*)d_in[8];
    const float* out_b  = (const float*)d_in[9];
    float* out = (float*)d_out;

    int B = out_size;                 // 8192
    int nnz = in_sizes[0] / 2;        // 262144
    int ft_in = in_sizes[4] / FT_OUT; // 40960

    // workspace layout (16B-aligned pieces)
    _Float16* W2h  = (_Float16*)d_ws;                          // ft_in*256 halfs (20 MB)
    int2*  slot_s  = (int2*)(W2h + (size_t)ft_in * FT_OUT);    // B*CAP entries (6 MB)
    int2*  slot_n  = slot_s + (size_t)B * CAP;                 // 6 MB
    int*   cnt_s   = (int*)(slot_n + (size_t)B * CAP);         // B*CPAD (512 KB)
    int*   cnt_n   = cnt_s + (size_t)B * CPAD;                 // B*CPAD

    int nfill  = 2 * ((nnz + 255) / 256);                      // 2048
    int nbuild = (ft_in / 64) * (FT_OUT / 64);                 // 2560

    hipMemsetAsync(cnt_s, 0, 2 * (size_t)B * CPAD * sizeof(int), stream);
    prep_k<<<nfill + nbuild, 256, 0, stream>>>(ft_w, fft_w, W2h, ft_in,
                                               stm, nstm, values, nnz,
                                               cnt_s, cnt_n, slot_s, slot_n, nfill);
    fused_k<<<B / 2, 256, 0, stream>>>(W2h, cnt_s, slot_s, cnt_n, slot_n,
                                       ft_b, fft_b, out_w, out_b, out, B);
}